// Round 6
// baseline (361.871 us; speedup 1.0000x reference)
//
#include <hip/hip_runtime.h>

#define E_EDGES 800000
#define NN 50000
#define OUT_STRIDE 288

typedef __bf16 bf16;
typedef bf16 bf16x8 __attribute__((ext_vector_type(8)));
typedef float floatx4 __attribute__((ext_vector_type(4)));
typedef float floatx2 __attribute__((ext_vector_type(2)));
typedef unsigned short ushort8v __attribute__((ext_vector_type(8)));

__device__ __forceinline__ unsigned short f2bf(float f){
    return __builtin_bit_cast(unsigned short, (bf16)f);
}
__device__ __forceinline__ unsigned pack2bf(float a, float b){
    unsigned short lo = __builtin_bit_cast(unsigned short, (bf16)a);
    unsigned short hi = __builtin_bit_cast(unsigned short, (bf16)b);
    return (unsigned)lo | ((unsigned)hi << 16);
}
// monotone float<->uint for atomicMax/Min
__device__ __forceinline__ unsigned encf(float f){
    unsigned u = __float_as_uint(f);
    return (u & 0x80000000u) ? ~u : (u | 0x80000000u);
}
__device__ __forceinline__ float decf(unsigned u){
    return __uint_as_float((u & 0x80000000u) ? (u ^ 0x80000000u) : ~u);
}
__device__ __forceinline__ floatx4 mfma16(ushort8v a, ushort8v b, floatx4 c){
    return __builtin_amdgcn_mfma_f32_16x16x32_bf16(
        __builtin_bit_cast(bf16x8, a), __builtin_bit_cast(bf16x8, b), c, 0, 0, 0);
}
__device__ __forceinline__ void flush_run(float* out, int node, float s, float mx, float mn, int lane){
    float* sp = out + (long)node * OUT_STRIDE + 64;
    atomicAdd(sp + lane, s);
    atomicMax((unsigned*)sp + 64 + lane, encf(mx));
    atomicMin((unsigned*)sp + 128 + lane, encf(mn));
}
// h1 = relu(P(fp8) + Q(fp8)) -> bf16 B-frag
__device__ __forceinline__ ushort8v combine_relu_fp8(uint2 p, uint2 q){
    floatx2 p01 = __builtin_amdgcn_cvt_pk_f32_fp8((int)p.x, false);
    floatx2 p23 = __builtin_amdgcn_cvt_pk_f32_fp8((int)p.x, true);
    floatx2 p45 = __builtin_amdgcn_cvt_pk_f32_fp8((int)p.y, false);
    floatx2 p67 = __builtin_amdgcn_cvt_pk_f32_fp8((int)p.y, true);
    floatx2 q01 = __builtin_amdgcn_cvt_pk_f32_fp8((int)q.x, false);
    floatx2 q23 = __builtin_amdgcn_cvt_pk_f32_fp8((int)q.x, true);
    floatx2 q45 = __builtin_amdgcn_cvt_pk_f32_fp8((int)q.y, false);
    floatx2 q67 = __builtin_amdgcn_cvt_pk_f32_fp8((int)q.y, true);
    floatx2 s01 = p01 + q01, s23 = p23 + q23, s45 = p45 + q45, s67 = p67 + q67;
    uint4 o;
    o.x = pack2bf(fmaxf(s01[0], 0.f), fmaxf(s01[1], 0.f));
    o.y = pack2bf(fmaxf(s23[0], 0.f), fmaxf(s23[1], 0.f));
    o.z = pack2bf(fmaxf(s45[0], 0.f), fmaxf(s45[1], 0.f));
    o.w = pack2bf(fmaxf(s67[0], 0.f), fmaxf(s67[1], 0.f));
    return __builtin_bit_cast(ushort8v, o);
}

// ---------------- setup: init out accum | prepack weights | hist ----------------
#define INIT_N 2400000
#define PK_N   40960
#define SETUP_TOTAL (INIT_N + PK_N + E_EDGES)

__global__ void setup_kernel(const int* __restrict__ ei,
                             const float* __restrict__ W1, const float* __restrict__ W2,
                             const float* __restrict__ W3,
                             unsigned short* __restrict__ wp,
                             int* __restrict__ cnt, float* __restrict__ out)
{
    int i = blockIdx.x * blockDim.x + threadIdx.x;
    if (i < INIT_N) {
        // out row: [x 0..16 | sum 16..32 | max 32..48 | min 48..64 | u 64..72] uint4 units
        int row = i / 48, q = i % 48;
        uint4 val = (q < 32) ? make_uint4(0u, 0u, 0u, 0u)
                             : make_uint4(~0u, ~0u, ~0u, ~0u);
        ((uint4*)out)[(long)row * 72 + 16 + q] = val;
        return;
    }
    i -= INIT_N;
    if (i < PK_N) {
        // A-fragment pack (weights as A): wp[f*8+j] = W[kc*32+quad*8+j][nt*16+ln]
        const float* W; int N; int idx;
        if (i < 16384)      { W = W1; N = 128; idx = i; }
        else if (i < 32768) { W = W2; N = 128; idx = i - 16384; }
        else                { W = W3; N = 64;  idx = i - 32768; }
        int j = idx & 7, lane = (idx >> 3) & 63, kc = (idx >> 9) & 3, nt = idx >> 11;
        wp[i] = f2bf(W[(kc * 32 + ((lane >> 4) & 3) * 8 + j) * N + nt * 16 + (lane & 15)]);
        return;
    }
    i -= PK_N;
    if (i < E_EDGES) atomicAdd(&cnt[ei[E_EDGES + i]], 1);
}

// ---------------- per-node P/Q precompute ----------------
// P[n] = x[n]*W1a + b1, Q[n] = x[n]*W1b -> fp8 e4m3, 128ch each, stored in
// GATHER-ORDER: byte index g(ch) = q*32 + kc*8 + j for ch = kc*32 + q*8 + j,
// so the edge kernel reads one contiguous 32B (= 2x uint4) run per lane.
#define PQ_BLOCKS 391
__global__ __launch_bounds__(256, 4) void pq_kernel(
    const float* __restrict__ x, const unsigned short* __restrict__ wp,
    const float* __restrict__ b1,
    unsigned char* __restrict__ pb, unsigned char* __restrict__ qb)
{
    const int tid = threadIdx.x, lane = tid & 63, w = tid >> 6;
    const int quad = lane >> 4, ln = lane & 15;
    const ushort8v* wpv = (const ushort8v*)wp;
    const int nbase = (blockIdx.x * 4 + w) * 32;
    const int n0 = nbase + ln, n1 = nbase + 16 + ln;
    const int n0c = min(n0, NN - 1), n1c = min(n1, NN - 1);

    ushort8v X0[2], X1[2];
#pragma unroll
    for (int c = 0; c < 2; c++){
        const float4* p0 = (const float4*)(x + (long)n0c * 64 + c * 32 + quad * 8);
        const float4* p1 = (const float4*)(x + (long)n1c * 64 + c * 32 + quad * 8);
        float4 a = p0[0], b = p0[1];
        float4 cc = p1[0], d = p1[1];
        uint4 u0, u1;
        u0.x = pack2bf(a.x, a.y);  u0.y = pack2bf(a.z, a.w);
        u0.z = pack2bf(b.x, b.y);  u0.w = pack2bf(b.z, b.w);
        u1.x = pack2bf(cc.x, cc.y); u1.y = pack2bf(cc.z, cc.w);
        u1.z = pack2bf(d.x, d.y);  u1.w = pack2bf(d.z, d.w);
        X0[c] = __builtin_bit_cast(ushort8v, u0);
        X1[c] = __builtin_bit_cast(ushort8v, u1);
    }
#pragma unroll
    for (int nt = 0; nt < 8; nt++){
        floatx4 bini = *(const floatx4*)(b1 + nt * 16 + quad * 4);
        floatx4 z = {0.f, 0.f, 0.f, 0.f};
        floatx4 aP0 = bini, aP1 = bini, aQ0 = z, aQ1 = z;
        ushort8v Af0 = wpv[(nt * 4 + 0) * 64 + lane];
        ushort8v Af1 = wpv[(nt * 4 + 1) * 64 + lane];
        ushort8v Af2 = wpv[(nt * 4 + 2) * 64 + lane];
        ushort8v Af3 = wpv[(nt * 4 + 3) * 64 + lane];
        aP0 = mfma16(Af0, X0[0], aP0); aP0 = mfma16(Af1, X0[1], aP0);
        aP1 = mfma16(Af0, X1[0], aP1); aP1 = mfma16(Af1, X1[1], aP1);
        aQ0 = mfma16(Af2, X0[0], aQ0); aQ0 = mfma16(Af3, X0[1], aQ0);
        aQ1 = mfma16(Af2, X1[0], aQ1); aQ1 = mfma16(Af3, X1[1], aQ1);
        int p0p = __builtin_amdgcn_cvt_pk_fp8_f32(aP0[0], aP0[1], 0, false);
        p0p     = __builtin_amdgcn_cvt_pk_fp8_f32(aP0[2], aP0[3], p0p, true);
        int p1p = __builtin_amdgcn_cvt_pk_fp8_f32(aP1[0], aP1[1], 0, false);
        p1p     = __builtin_amdgcn_cvt_pk_fp8_f32(aP1[2], aP1[3], p1p, true);
        int q0p = __builtin_amdgcn_cvt_pk_fp8_f32(aQ0[0], aQ0[1], 0, false);
        q0p     = __builtin_amdgcn_cvt_pk_fp8_f32(aQ0[2], aQ0[3], q0p, true);
        int q1p = __builtin_amdgcn_cvt_pk_fp8_f32(aQ1[0], aQ1[1], 0, false);
        q1p     = __builtin_amdgcn_cvt_pk_fp8_f32(aQ1[2], aQ1[3], q1p, true);
        // gather-order byte offset for channels och = nt*16 + quad*4 + (0..3)
        int g0 = ((nt & 1) * 2 + (quad >> 1)) * 32 + (nt >> 1) * 8 + (quad & 1) * 4;
        if (n0 < NN){
            *(int*)(pb + (long)n0 * 128 + g0) = p0p;
            *(int*)(qb + (long)n0 * 128 + g0) = q0p;
        }
        if (n1 < NN){
            *(int*)(pb + (long)n1 * 128 + g0) = p1p;
            *(int*)(qb + (long)n1 * 128 + g0) = q1p;
        }
    }
}

// ---------------- counting sort by destination ----------------
__global__ void scanA_kernel(const int* __restrict__ cnt, int* __restrict__ off,
                             int* __restrict__ bsum){
    __shared__ int s[256];
    int tid = threadIdx.x;
    int node = blockIdx.x * 196 + tid;
    int val = (tid < 196 && node < NN) ? cnt[node] : 0;
    s[tid] = val;
    __syncthreads();
    for (int d = 1; d < 256; d <<= 1){
        int t = (tid >= d) ? s[tid - d] : 0;
        __syncthreads();
        s[tid] += t;
        __syncthreads();
    }
    if (tid < 196 && node < NN) off[node] = s[tid] - val;  // local exclusive
    if (tid == 255) bsum[blockIdx.x] = s[255];             // block total
}

__global__ void scanB_kernel(const int* __restrict__ bsum, int* __restrict__ bbase){
    __shared__ int s[256];
    int tid = threadIdx.x;
    int val = bsum[tid];
    s[tid] = val;
    __syncthreads();
    for (int d = 1; d < 256; d <<= 1){
        int t = (tid >= d) ? s[tid - d] : 0;
        __syncthreads();
        s[tid] += t;
        __syncthreads();
    }
    bbase[tid] = s[tid] - val;  // exclusive
}

// scatter (+ fused scanC): global pos = local excl + block base; packed u32 ids
__global__ void scatter_kernel(const int* __restrict__ ei, int* __restrict__ off,
                               const int* __restrict__ bbase, unsigned* __restrict__ enodes){
    int e = blockIdx.x * blockDim.x + threadIdx.x;
    if (e >= E_EDGES) return;
    int c = ei[E_EDGES + e], r = ei[e];
    int pos = atomicAdd(&off[c], 1) + bbase[c / 196];
    enodes[pos] = (unsigned)r | ((unsigned)c << 16);   // both < 65536
}

// ---------------- edge MLP: 32 edges per wave-tile, barrier-free ----------------
// 8 blocks/CU (19456B LDS/block, 155.6/160 KB). Gather: 2x16B per node record.
// T tile bf16 LD=38 u16 (stride 19 dwords, gcd(19,32)=1 -> conflict-free reads).
// Epilogue: two independent 16-edge run-reduce chains (atomics merge boundary).
__global__ __launch_bounds__(256, 8) void edge_mlp_kernel(
    const unsigned* __restrict__ enodes, const unsigned short* __restrict__ wp,
    const unsigned char* __restrict__ pb, const unsigned char* __restrict__ qb,
    const float* __restrict__ b2, const float* __restrict__ b3,
    float* __restrict__ out)
{
    __shared__ __align__(16) unsigned char smem[4 * 4864];

    const int tid  = threadIdx.x;
    const int lane = tid & 63;
    const int w    = tid >> 6;
    const int quad = lane >> 4;
    const int ln   = lane & 15;
    unsigned short* wbuf = (unsigned short*)(smem + w * 4864);  // L2: 32x72 u16; T: 64x38 u16
    const ushort8v* wpv = (const ushort8v*)wp;

    const int g = blockIdx.x * 4 + w;       // tile id, 25000 total
    const int ebase = g * 32;
    unsigned e0 = enodes[ebase + ln];
    unsigned e1 = enodes[ebase + 16 + ln];
    const int r0 = (int)(e0 & 0xFFFFu), cn0 = (int)(e0 >> 16);
    const int r1 = (int)(e1 & 0xFFFFu), cn1 = (int)(e1 >> 16);

    // ---- "layer 1": gather P[row] + Q[col] (fp8, gather-order) -> h1 B-frags ----
    ushort8v H0[4], H1[4];
    {
        const long po = (long)quad * 32;
        uint4 pA = *(const uint4*)(pb + (long)r0  * 128 + po);
        uint4 pB = *(const uint4*)(pb + (long)r0  * 128 + po + 16);
        uint4 qA = *(const uint4*)(qb + (long)cn0 * 128 + po);
        uint4 qB = *(const uint4*)(qb + (long)cn0 * 128 + po + 16);
        uint4 rA = *(const uint4*)(pb + (long)r1  * 128 + po);
        uint4 rB = *(const uint4*)(pb + (long)r1  * 128 + po + 16);
        uint4 sA = *(const uint4*)(qb + (long)cn1 * 128 + po);
        uint4 sB = *(const uint4*)(qb + (long)cn1 * 128 + po + 16);
        H0[0] = combine_relu_fp8(make_uint2(pA.x, pA.y), make_uint2(qA.x, qA.y));
        H0[1] = combine_relu_fp8(make_uint2(pA.z, pA.w), make_uint2(qA.z, qA.w));
        H0[2] = combine_relu_fp8(make_uint2(pB.x, pB.y), make_uint2(qB.x, qB.y));
        H0[3] = combine_relu_fp8(make_uint2(pB.z, pB.w), make_uint2(qB.z, qB.w));
        H1[0] = combine_relu_fp8(make_uint2(rA.x, rA.y), make_uint2(sA.x, sA.y));
        H1[1] = combine_relu_fp8(make_uint2(rA.z, rA.w), make_uint2(sA.z, sA.w));
        H1[2] = combine_relu_fp8(make_uint2(rB.x, rB.y), make_uint2(sB.x, sB.y));
        H1[3] = combine_relu_fp8(make_uint2(rB.z, rB.w), make_uint2(sB.z, sB.w));
    }

    // ---- layer 2 (sets 8..15), two half-passes of 64 och each ----
    ushort8v G0[4], G1[4];
#pragma unroll
    for (int hv = 0; hv < 2; hv++){
#pragma unroll
        for (int q2 = 0; q2 < 4; q2++){
            int nt = hv * 4 + q2;
            floatx4 bini = *(const floatx4*)(b2 + nt * 16 + quad * 4);
            floatx4 a0 = bini, a1 = bini;
#pragma unroll
            for (int kc = 0; kc < 4; kc++){
                ushort8v Af = wpv[2048 + (nt * 4 + kc) * 64 + lane];
                a0 = mfma16(Af, H0[kc], a0);
                a1 = mfma16(Af, H1[kc], a1);
            }
            uint2 p0, p1;
            p0.x = pack2bf(fmaxf(a0[0], 0.f), fmaxf(a0[1], 0.f));
            p0.y = pack2bf(fmaxf(a0[2], 0.f), fmaxf(a0[3], 0.f));
            p1.x = pack2bf(fmaxf(a1[0], 0.f), fmaxf(a1[1], 0.f));
            p1.y = pack2bf(fmaxf(a1[2], 0.f), fmaxf(a1[3], 0.f));
            int col = q2 * 16 + quad * 4;
            *(uint2*)(wbuf + ln * 72 + col)        = p0;
            *(uint2*)(wbuf + (16 + ln) * 72 + col) = p1;
        }
#pragma unroll
        for (int c = 0; c < 2; c++){
            G0[hv * 2 + c] = *(const ushort8v*)(wbuf + ln * 72 + c * 32 + quad * 8);
            G1[hv * 2 + c] = *(const ushort8v*)(wbuf + (16 + ln) * 72 + c * 32 + quad * 8);
        }
    }

    // ---- layer 3 (sets 16..19) -> T bf16 [och 64][edge 32], LD=38 u16 ----
#pragma unroll
    for (int nt = 0; nt < 4; nt++){
        floatx4 bini = *(const floatx4*)(b3 + nt * 16 + quad * 4);
        floatx4 a0 = bini, a1 = bini;
#pragma unroll
        for (int kc = 0; kc < 4; kc++){
            ushort8v Af = wpv[4096 + (nt * 4 + kc) * 64 + lane];
            a0 = mfma16(Af, G0[kc], a0);
            a1 = mfma16(Af, G1[kc], a1);
        }
        int och = nt * 16 + quad * 4;
#pragma unroll
        for (int r = 0; r < 4; r++){
            wbuf[(och + r) * 38 + ln]      = f2bf(a0[r]);
            wbuf[(och + r) * 38 + 16 + ln] = f2bf(a1[r]);
        }
    }

    // ---- epilogue: lane = channel; two independent 16-edge run-reduce chains ----
    float v[32];
#pragma unroll
    for (int t = 0; t < 8; t++){
        unsigned a = *(const unsigned*)(wbuf + lane * 38 + t * 4);      // 4B-aligned
        unsigned b = *(const unsigned*)(wbuf + lane * 38 + t * 4 + 2);
        v[t * 4 + 0] = __uint_as_float(a << 16);
        v[t * 4 + 1] = __uint_as_float(a & 0xFFFF0000u);
        v[t * 4 + 2] = __uint_as_float(b << 16);
        v[t * 4 + 3] = __uint_as_float(b & 0xFFFF0000u);
    }
    int curA = __builtin_amdgcn_readlane(cn0, 0);
    int curB = __builtin_amdgcn_readlane(cn1, 0);
    float sA = v[0],  mxA = v[0],  mnA = v[0];
    float sB = v[16], mxB = v[16], mnB = v[16];
#pragma unroll
    for (int j = 1; j < 16; j++){
        int njA = __builtin_amdgcn_readlane(cn0, j);
        int njB = __builtin_amdgcn_readlane(cn1, j);
        if (njA != curA){
            flush_run(out, curA, sA, mxA, mnA, lane);
            curA = njA; sA = v[j]; mxA = v[j]; mnA = v[j];
        } else {
            sA += v[j]; mxA = fmaxf(mxA, v[j]); mnA = fminf(mnA, v[j]);
        }
        if (njB != curB){
            flush_run(out, curB, sB, mxB, mnB, lane);
            curB = njB; sB = v[16 + j]; mxB = v[16 + j]; mnB = v[16 + j];
        } else {
            sB += v[16 + j]; mxB = fmaxf(mxB, v[16 + j]); mnB = fminf(mnB, v[16 + j]);
        }
    }
    flush_run(out, curA, sA, mxA, mnA, lane);
    flush_run(out, curB, sB, mxB, mnB, lane);
}

// ---------------- finalize ----------------
__global__ void finalize_kernel(const float* __restrict__ x, const float* __restrict__ u,
                                const int* __restrict__ batch, const int* __restrict__ cnt,
                                float* __restrict__ out)
{
    long i = (long)blockIdx.x * blockDim.x + threadIdx.x;
    if (i >= (long)NN * 72) return;
    int ndx = (int)(i / 72);
    int q   = (int)(i % 72);
    float4 res;
    if (q < 16) {
        res = ((const float4*)(x + (long)ndx * 64))[q];
    } else if (q < 32) {
        float4 sv = ((const float4*)out)[i];
        int k = cnt[ndx];
        float inv = 1.f / (float)(k > 0 ? k : 1);
        res.x = sv.x * inv; res.y = sv.y * inv; res.z = sv.z * inv; res.w = sv.w * inv;
    } else if (q < 64) {
        uint4 e = ((const uint4*)out)[i];
        bool ne = cnt[ndx] > 0;
        res.x = ne ? decf(e.x) : 0.f; res.y = ne ? decf(e.y) : 0.f;
        res.z = ne ? decf(e.z) : 0.f; res.w = ne ? decf(e.w) : 0.f;
    } else {
        res = ((const float4*)(u + (long)batch[ndx] * 32))[q - 64];
    }
    ((float4*)out)[i] = res;
}

extern "C" void kernel_launch(void* const* d_in, const int* in_sizes, int n_in,
                              void* d_out, int out_size, void* d_ws, size_t ws_size,
                              hipStream_t stream)
{
    const float* x     = (const float*)d_in[0];
    const int*   ei    = (const int*)d_in[1];
    // d_in[2] = edge_attr (unused)
    const float* u     = (const float*)d_in[3];
    const int*   batch = (const int*)d_in[4];
    const float* W1    = (const float*)d_in[5];
    const float* b1    = (const float*)d_in[6];
    const float* W2    = (const float*)d_in[7];
    const float* b2    = (const float*)d_in[8];
    const float* W3    = (const float*)d_in[9];
    const float* b3    = (const float*)d_in[10];
    float* out = (float*)d_out;
    unsigned char* ws = (unsigned char*)d_ws;

    // ws layout: wp | cnt | off | bsum | bbase | enodes(u32) | P fp8 | Q fp8
    unsigned short* wp     = (unsigned short*)ws;              //    81,920 B
    int*            cnt    = (int*)(ws + 81920);               //   200,000 B
    int*            off    = (int*)(ws + 281920);              //   200,000 B
    int*            bsum   = (int*)(ws + 481920);              //     1,024 B
    int*            bbase  = (int*)(ws + 482944);              //     1,024 B
    unsigned*       enodes = (unsigned*)(ws + 483968);         // 3,200,000 B
    unsigned char*  pb     = (unsigned char*)(ws + 3683968);   // 6,400,000 B
    unsigned char*  qb     = (unsigned char*)(ws + 10083968);  // 6,400,000 B

    hipMemsetAsync(cnt, 0, 200000, stream);
    setup_kernel<<<(SETUP_TOTAL + 255) / 256, 256, 0, stream>>>(ei, W1, W2, W3, wp, cnt, out);
    pq_kernel<<<PQ_BLOCKS, 256, 0, stream>>>(x, wp, b1, pb, qb);
    scanA_kernel<<<256, 256, 0, stream>>>(cnt, off, bsum);
    scanB_kernel<<<1, 256, 0, stream>>>(bsum, bbase);
    scatter_kernel<<<(E_EDGES + 255) / 256, 256, 0, stream>>>(ei, off, bbase, enodes);
    edge_mlp_kernel<<<6250, 256, 0, stream>>>(enodes, wp, pb, qb, b2, b3, out);
    finalize_kernel<<<(int)(((long)NN * 72 + 255) / 256), 256, 0, stream>>>(x, u, batch, cnt, out);
}

// Round 7
// 336.893 us; speedup vs baseline: 1.0741x; 1.0741x over previous
//
#include <hip/hip_runtime.h>

#define E_EDGES 800000
#define NN 50000
#define OUT_STRIDE 288

typedef __bf16 bf16;
typedef bf16 bf16x8 __attribute__((ext_vector_type(8)));
typedef float floatx4 __attribute__((ext_vector_type(4)));
typedef float floatx2 __attribute__((ext_vector_type(2)));
typedef unsigned short ushort8v __attribute__((ext_vector_type(8)));

__device__ __forceinline__ unsigned short f2bf(float f){
    return __builtin_bit_cast(unsigned short, (bf16)f);
}
__device__ __forceinline__ unsigned pack2bf(float a, float b){
    unsigned short lo = __builtin_bit_cast(unsigned short, (bf16)a);
    unsigned short hi = __builtin_bit_cast(unsigned short, (bf16)b);
    return (unsigned)lo | ((unsigned)hi << 16);
}
// monotone float<->uint for atomicMax/Min
__device__ __forceinline__ unsigned encf(float f){
    unsigned u = __float_as_uint(f);
    return (u & 0x80000000u) ? ~u : (u | 0x80000000u);
}
__device__ __forceinline__ float decf(unsigned u){
    return __uint_as_float((u & 0x80000000u) ? (u ^ 0x80000000u) : ~u);
}
__device__ __forceinline__ floatx4 mfma16(ushort8v a, ushort8v b, floatx4 c){
    return __builtin_amdgcn_mfma_f32_16x16x32_bf16(
        __builtin_bit_cast(bf16x8, a), __builtin_bit_cast(bf16x8, b), c, 0, 0, 0);
}
__device__ __forceinline__ void flush_run(float* out, int node, float s, float mx, float mn, int lane){
    float* sp = out + (long)node * OUT_STRIDE + 64;
    atomicAdd(sp + lane, s);
    atomicMax((unsigned*)sp + 64 + lane, encf(mx));
    atomicMin((unsigned*)sp + 128 + lane, encf(mn));
}
// h1 = relu(P(fp8) + Q(fp8)) -> bf16 B-frag
__device__ __forceinline__ ushort8v combine_relu_fp8(uint2 p, uint2 q){
    floatx2 p01 = __builtin_amdgcn_cvt_pk_f32_fp8((int)p.x, false);
    floatx2 p23 = __builtin_amdgcn_cvt_pk_f32_fp8((int)p.x, true);
    floatx2 p45 = __builtin_amdgcn_cvt_pk_f32_fp8((int)p.y, false);
    floatx2 p67 = __builtin_amdgcn_cvt_pk_f32_fp8((int)p.y, true);
    floatx2 q01 = __builtin_amdgcn_cvt_pk_f32_fp8((int)q.x, false);
    floatx2 q23 = __builtin_amdgcn_cvt_pk_f32_fp8((int)q.x, true);
    floatx2 q45 = __builtin_amdgcn_cvt_pk_f32_fp8((int)q.y, false);
    floatx2 q67 = __builtin_amdgcn_cvt_pk_f32_fp8((int)q.y, true);
    floatx2 s01 = p01 + q01, s23 = p23 + q23, s45 = p45 + q45, s67 = p67 + q67;
    uint4 o;
    o.x = pack2bf(fmaxf(s01[0], 0.f), fmaxf(s01[1], 0.f));
    o.y = pack2bf(fmaxf(s23[0], 0.f), fmaxf(s23[1], 0.f));
    o.z = pack2bf(fmaxf(s45[0], 0.f), fmaxf(s45[1], 0.f));
    o.w = pack2bf(fmaxf(s67[0], 0.f), fmaxf(s67[1], 0.f));
    return __builtin_bit_cast(ushort8v, o);
}

// ---------------- setup: init out accum | prepack weights | hist ----------------
#define INIT_N 2400000
#define PK_N   40960
#define SETUP_TOTAL (INIT_N + PK_N + E_EDGES)

__global__ void setup_kernel(const int* __restrict__ ei,
                             const float* __restrict__ W1, const float* __restrict__ W2,
                             const float* __restrict__ W3,
                             unsigned short* __restrict__ wp,
                             int* __restrict__ cnt, float* __restrict__ out)
{
    int i = blockIdx.x * blockDim.x + threadIdx.x;
    if (i < INIT_N) {
        // out row: [x 0..16 | sum 16..32 | max 32..48 | min 48..64 | u 64..72] uint4 units
        int row = i / 48, q = i % 48;
        uint4 val = (q < 32) ? make_uint4(0u, 0u, 0u, 0u)
                             : make_uint4(~0u, ~0u, ~0u, ~0u);
        ((uint4*)out)[(long)row * 72 + 16 + q] = val;
        return;
    }
    i -= INIT_N;
    if (i < PK_N) {
        // A-fragment pack (weights as A): wp[f*8+j] = W[kc*32+quad*8+j][nt*16+ln]
        const float* W; int N; int idx;
        if (i < 16384)      { W = W1; N = 128; idx = i; }
        else if (i < 32768) { W = W2; N = 128; idx = i - 16384; }
        else                { W = W3; N = 64;  idx = i - 32768; }
        int j = idx & 7, lane = (idx >> 3) & 63, kc = (idx >> 9) & 3, nt = idx >> 11;
        wp[i] = f2bf(W[(kc * 32 + ((lane >> 4) & 3) * 8 + j) * N + nt * 16 + (lane & 15)]);
        return;
    }
    i -= PK_N;
    if (i < E_EDGES) atomicAdd(&cnt[ei[E_EDGES + i]], 1);
}

// ---------------- per-node P/Q precompute ----------------
// P[n] = x[n]*W1a + b1, Q[n] = x[n]*W1b -> fp8 e4m3, 128ch each, stored in
// GATHER-ORDER: byte index g(ch) = q*32 + kc*8 + j for ch = kc*32 + q*8 + j,
// so the edge kernel reads one contiguous 32B (= 2x uint4) run per lane.
#define PQ_BLOCKS 391
__global__ __launch_bounds__(256, 4) void pq_kernel(
    const float* __restrict__ x, const unsigned short* __restrict__ wp,
    const float* __restrict__ b1,
    unsigned char* __restrict__ pb, unsigned char* __restrict__ qb)
{
    const int tid = threadIdx.x, lane = tid & 63, w = tid >> 6;
    const int quad = lane >> 4, ln = lane & 15;
    const ushort8v* wpv = (const ushort8v*)wp;
    const int nbase = (blockIdx.x * 4 + w) * 32;
    const int n0 = nbase + ln, n1 = nbase + 16 + ln;
    const int n0c = min(n0, NN - 1), n1c = min(n1, NN - 1);

    ushort8v X0[2], X1[2];
#pragma unroll
    for (int c = 0; c < 2; c++){
        const float4* p0 = (const float4*)(x + (long)n0c * 64 + c * 32 + quad * 8);
        const float4* p1 = (const float4*)(x + (long)n1c * 64 + c * 32 + quad * 8);
        float4 a = p0[0], b = p0[1];
        float4 cc = p1[0], d = p1[1];
        uint4 u0, u1;
        u0.x = pack2bf(a.x, a.y);  u0.y = pack2bf(a.z, a.w);
        u0.z = pack2bf(b.x, b.y);  u0.w = pack2bf(b.z, b.w);
        u1.x = pack2bf(cc.x, cc.y); u1.y = pack2bf(cc.z, cc.w);
        u1.z = pack2bf(d.x, d.y);  u1.w = pack2bf(d.z, d.w);
        X0[c] = __builtin_bit_cast(ushort8v, u0);
        X1[c] = __builtin_bit_cast(ushort8v, u1);
    }
#pragma unroll
    for (int nt = 0; nt < 8; nt++){
        floatx4 bini = *(const floatx4*)(b1 + nt * 16 + quad * 4);
        floatx4 z = {0.f, 0.f, 0.f, 0.f};
        floatx4 aP0 = bini, aP1 = bini, aQ0 = z, aQ1 = z;
        ushort8v Af0 = wpv[(nt * 4 + 0) * 64 + lane];
        ushort8v Af1 = wpv[(nt * 4 + 1) * 64 + lane];
        ushort8v Af2 = wpv[(nt * 4 + 2) * 64 + lane];
        ushort8v Af3 = wpv[(nt * 4 + 3) * 64 + lane];
        aP0 = mfma16(Af0, X0[0], aP0); aP0 = mfma16(Af1, X0[1], aP0);
        aP1 = mfma16(Af0, X1[0], aP1); aP1 = mfma16(Af1, X1[1], aP1);
        aQ0 = mfma16(Af2, X0[0], aQ0); aQ0 = mfma16(Af3, X0[1], aQ0);
        aQ1 = mfma16(Af2, X1[0], aQ1); aQ1 = mfma16(Af3, X1[1], aQ1);
        int p0p = __builtin_amdgcn_cvt_pk_fp8_f32(aP0[0], aP0[1], 0, false);
        p0p     = __builtin_amdgcn_cvt_pk_fp8_f32(aP0[2], aP0[3], p0p, true);
        int p1p = __builtin_amdgcn_cvt_pk_fp8_f32(aP1[0], aP1[1], 0, false);
        p1p     = __builtin_amdgcn_cvt_pk_fp8_f32(aP1[2], aP1[3], p1p, true);
        int q0p = __builtin_amdgcn_cvt_pk_fp8_f32(aQ0[0], aQ0[1], 0, false);
        q0p     = __builtin_amdgcn_cvt_pk_fp8_f32(aQ0[2], aQ0[3], q0p, true);
        int q1p = __builtin_amdgcn_cvt_pk_fp8_f32(aQ1[0], aQ1[1], 0, false);
        q1p     = __builtin_amdgcn_cvt_pk_fp8_f32(aQ1[2], aQ1[3], q1p, true);
        // gather-order byte offset for channels och = nt*16 + quad*4 + (0..3)
        int g0 = ((nt & 1) * 2 + (quad >> 1)) * 32 + (nt >> 1) * 8 + (quad & 1) * 4;
        if (n0 < NN){
            *(int*)(pb + (long)n0 * 128 + g0) = p0p;
            *(int*)(qb + (long)n0 * 128 + g0) = q0p;
        }
        if (n1 < NN){
            *(int*)(pb + (long)n1 * 128 + g0) = p1p;
            *(int*)(qb + (long)n1 * 128 + g0) = q1p;
        }
    }
}

// ---------------- counting sort by destination ----------------
__global__ void scanA_kernel(const int* __restrict__ cnt, int* __restrict__ off,
                             int* __restrict__ bsum){
    __shared__ int s[256];
    int tid = threadIdx.x;
    int node = blockIdx.x * 196 + tid;
    int val = (tid < 196 && node < NN) ? cnt[node] : 0;
    s[tid] = val;
    __syncthreads();
    for (int d = 1; d < 256; d <<= 1){
        int t = (tid >= d) ? s[tid - d] : 0;
        __syncthreads();
        s[tid] += t;
        __syncthreads();
    }
    if (tid < 196 && node < NN) off[node] = s[tid] - val;  // local exclusive
    if (tid == 255) bsum[blockIdx.x] = s[255];             // block total
}

__global__ void scanB_kernel(const int* __restrict__ bsum, int* __restrict__ bbase){
    __shared__ int s[256];
    int tid = threadIdx.x;
    int val = bsum[tid];
    s[tid] = val;
    __syncthreads();
    for (int d = 1; d < 256; d <<= 1){
        int t = (tid >= d) ? s[tid - d] : 0;
        __syncthreads();
        s[tid] += t;
        __syncthreads();
    }
    bbase[tid] = s[tid] - val;  // exclusive
}

// scatter (+ fused scanC): global pos = local excl + block base; packed u32 ids
__global__ void scatter_kernel(const int* __restrict__ ei, int* __restrict__ off,
                               const int* __restrict__ bbase, unsigned* __restrict__ enodes){
    int e = blockIdx.x * blockDim.x + threadIdx.x;
    if (e >= E_EDGES) return;
    int c = ei[E_EDGES + e], r = ei[e];
    int pos = atomicAdd(&off[c], 1) + bbase[c / 196];
    enodes[pos] = (unsigned)r | ((unsigned)c << 16);   // both < 65536
}

// ---------------- edge MLP: 32 edges per wave-tile, barrier-free ----------------
// __launch_bounds__(256,6): register budget ~84/wave (round-6's (256,8) capped
// the unified VGPR/AGPR budget at 64 -> fragment spill to scratch, WRITE_SIZE
// 61->260MB, 13% slower. 6 blocks/CU is the spill-free occupancy sweet spot.)
// Gather: 2x16B contiguous per node record (gather-order P/Q layout).
// T tile bf16 LD=38 u16; epilogue: two independent 16-edge run-reduce chains.
__global__ __launch_bounds__(256, 6) void edge_mlp_kernel(
    const unsigned* __restrict__ enodes, const unsigned short* __restrict__ wp,
    const unsigned char* __restrict__ pb, const unsigned char* __restrict__ qb,
    const float* __restrict__ b2, const float* __restrict__ b3,
    float* __restrict__ out)
{
    __shared__ __align__(16) unsigned char smem[4 * 4864];

    const int tid  = threadIdx.x;
    const int lane = tid & 63;
    const int w    = tid >> 6;
    const int quad = lane >> 4;
    const int ln   = lane & 15;
    unsigned short* wbuf = (unsigned short*)(smem + w * 4864);  // L2: 32x72 u16; T: 64x38 u16
    const ushort8v* wpv = (const ushort8v*)wp;

    const int g = blockIdx.x * 4 + w;       // tile id, 25000 total
    const int ebase = g * 32;
    unsigned e0 = enodes[ebase + ln];
    unsigned e1 = enodes[ebase + 16 + ln];
    const int r0 = (int)(e0 & 0xFFFFu), cn0 = (int)(e0 >> 16);
    const int r1 = (int)(e1 & 0xFFFFu), cn1 = (int)(e1 >> 16);

    // ---- "layer 1": gather P[row] + Q[col] (fp8, gather-order) -> h1 B-frags ----
    ushort8v H0[4], H1[4];
    {
        const long po = (long)quad * 32;
        uint4 pA = *(const uint4*)(pb + (long)r0  * 128 + po);
        uint4 pB = *(const uint4*)(pb + (long)r0  * 128 + po + 16);
        uint4 qA = *(const uint4*)(qb + (long)cn0 * 128 + po);
        uint4 qB = *(const uint4*)(qb + (long)cn0 * 128 + po + 16);
        uint4 rA = *(const uint4*)(pb + (long)r1  * 128 + po);
        uint4 rB = *(const uint4*)(pb + (long)r1  * 128 + po + 16);
        uint4 sA = *(const uint4*)(qb + (long)cn1 * 128 + po);
        uint4 sB = *(const uint4*)(qb + (long)cn1 * 128 + po + 16);
        H0[0] = combine_relu_fp8(make_uint2(pA.x, pA.y), make_uint2(qA.x, qA.y));
        H0[1] = combine_relu_fp8(make_uint2(pA.z, pA.w), make_uint2(qA.z, qA.w));
        H0[2] = combine_relu_fp8(make_uint2(pB.x, pB.y), make_uint2(qB.x, qB.y));
        H0[3] = combine_relu_fp8(make_uint2(pB.z, pB.w), make_uint2(qB.z, qB.w));
        H1[0] = combine_relu_fp8(make_uint2(rA.x, rA.y), make_uint2(sA.x, sA.y));
        H1[1] = combine_relu_fp8(make_uint2(rA.z, rA.w), make_uint2(sA.z, sA.w));
        H1[2] = combine_relu_fp8(make_uint2(rB.x, rB.y), make_uint2(sB.x, sB.y));
        H1[3] = combine_relu_fp8(make_uint2(rB.z, rB.w), make_uint2(sB.z, sB.w));
    }

    // ---- layer 2 (sets 8..15), two half-passes of 64 och each ----
    ushort8v G0[4], G1[4];
#pragma unroll
    for (int hv = 0; hv < 2; hv++){
#pragma unroll
        for (int q2 = 0; q2 < 4; q2++){
            int nt = hv * 4 + q2;
            floatx4 bini = *(const floatx4*)(b2 + nt * 16 + quad * 4);
            floatx4 a0 = bini, a1 = bini;
#pragma unroll
            for (int kc = 0; kc < 4; kc++){
                ushort8v Af = wpv[2048 + (nt * 4 + kc) * 64 + lane];
                a0 = mfma16(Af, H0[kc], a0);
                a1 = mfma16(Af, H1[kc], a1);
            }
            uint2 p0, p1;
            p0.x = pack2bf(fmaxf(a0[0], 0.f), fmaxf(a0[1], 0.f));
            p0.y = pack2bf(fmaxf(a0[2], 0.f), fmaxf(a0[3], 0.f));
            p1.x = pack2bf(fmaxf(a1[0], 0.f), fmaxf(a1[1], 0.f));
            p1.y = pack2bf(fmaxf(a1[2], 0.f), fmaxf(a1[3], 0.f));
            int col = q2 * 16 + quad * 4;
            *(uint2*)(wbuf + ln * 72 + col)        = p0;
            *(uint2*)(wbuf + (16 + ln) * 72 + col) = p1;
        }
#pragma unroll
        for (int c = 0; c < 2; c++){
            G0[hv * 2 + c] = *(const ushort8v*)(wbuf + ln * 72 + c * 32 + quad * 8);
            G1[hv * 2 + c] = *(const ushort8v*)(wbuf + (16 + ln) * 72 + c * 32 + quad * 8);
        }
    }

    // ---- layer 3 (sets 16..19) -> T bf16 [och 64][edge 32], LD=38 u16 ----
#pragma unroll
    for (int nt = 0; nt < 4; nt++){
        floatx4 bini = *(const floatx4*)(b3 + nt * 16 + quad * 4);
        floatx4 a0 = bini, a1 = bini;
#pragma unroll
        for (int kc = 0; kc < 4; kc++){
            ushort8v Af = wpv[4096 + (nt * 4 + kc) * 64 + lane];
            a0 = mfma16(Af, G0[kc], a0);
            a1 = mfma16(Af, G1[kc], a1);
        }
        int och = nt * 16 + quad * 4;
#pragma unroll
        for (int r = 0; r < 4; r++){
            wbuf[(och + r) * 38 + ln]      = f2bf(a0[r]);
            wbuf[(och + r) * 38 + 16 + ln] = f2bf(a1[r]);
        }
    }

    // ---- epilogue: lane = channel; two independent 16-edge run-reduce chains ----
    float v[32];
#pragma unroll
    for (int t = 0; t < 8; t++){
        unsigned a = *(const unsigned*)(wbuf + lane * 38 + t * 4);      // 4B-aligned
        unsigned b = *(const unsigned*)(wbuf + lane * 38 + t * 4 + 2);
        v[t * 4 + 0] = __uint_as_float(a << 16);
        v[t * 4 + 1] = __uint_as_float(a & 0xFFFF0000u);
        v[t * 4 + 2] = __uint_as_float(b << 16);
        v[t * 4 + 3] = __uint_as_float(b & 0xFFFF0000u);
    }
    int curA = __builtin_amdgcn_readlane(cn0, 0);
    int curB = __builtin_amdgcn_readlane(cn1, 0);
    float sA = v[0],  mxA = v[0],  mnA = v[0];
    float sB = v[16], mxB = v[16], mnB = v[16];
#pragma unroll
    for (int j = 1; j < 16; j++){
        int njA = __builtin_amdgcn_readlane(cn0, j);
        int njB = __builtin_amdgcn_readlane(cn1, j);
        if (njA != curA){
            flush_run(out, curA, sA, mxA, mnA, lane);
            curA = njA; sA = v[j]; mxA = v[j]; mnA = v[j];
        } else {
            sA += v[j]; mxA = fmaxf(mxA, v[j]); mnA = fminf(mnA, v[j]);
        }
        if (njB != curB){
            flush_run(out, curB, sB, mxB, mnB, lane);
            curB = njB; sB = v[16 + j]; mxB = v[16 + j]; mnB = v[16 + j];
        } else {
            sB += v[16 + j]; mxB = fmaxf(mxB, v[16 + j]); mnB = fminf(mnB, v[16 + j]);
        }
    }
    flush_run(out, curA, sA, mxA, mnA, lane);
    flush_run(out, curB, sB, mxB, mnB, lane);
}

// ---------------- finalize ----------------
__global__ void finalize_kernel(const float* __restrict__ x, const float* __restrict__ u,
                                const int* __restrict__ batch, const int* __restrict__ cnt,
                                float* __restrict__ out)
{
    long i = (long)blockIdx.x * blockDim.x + threadIdx.x;
    if (i >= (long)NN * 72) return;
    int ndx = (int)(i / 72);
    int q   = (int)(i % 72);
    float4 res;
    if (q < 16) {
        res = ((const float4*)(x + (long)ndx * 64))[q];
    } else if (q < 32) {
        float4 sv = ((const float4*)out)[i];
        int k = cnt[ndx];
        float inv = 1.f / (float)(k > 0 ? k : 1);
        res.x = sv.x * inv; res.y = sv.y * inv; res.z = sv.z * inv; res.w = sv.w * inv;
    } else if (q < 64) {
        uint4 e = ((const uint4*)out)[i];
        bool ne = cnt[ndx] > 0;
        res.x = ne ? decf(e.x) : 0.f; res.y = ne ? decf(e.y) : 0.f;
        res.z = ne ? decf(e.z) : 0.f; res.w = ne ? decf(e.w) : 0.f;
    } else {
        res = ((const float4*)(u + (long)batch[ndx] * 32))[q - 64];
    }
    ((float4*)out)[i] = res;
}

extern "C" void kernel_launch(void* const* d_in, const int* in_sizes, int n_in,
                              void* d_out, int out_size, void* d_ws, size_t ws_size,
                              hipStream_t stream)
{
    const float* x     = (const float*)d_in[0];
    const int*   ei    = (const int*)d_in[1];
    // d_in[2] = edge_attr (unused)
    const float* u     = (const float*)d_in[3];
    const int*   batch = (const int*)d_in[4];
    const float* W1    = (const float*)d_in[5];
    const float* b1    = (const float*)d_in[6];
    const float* W2    = (const float*)d_in[7];
    const float* b2    = (const float*)d_in[8];
    const float* W3    = (const float*)d_in[9];
    const float* b3    = (const float*)d_in[10];
    float* out = (float*)d_out;
    unsigned char* ws = (unsigned char*)d_ws;

    // ws layout: wp | cnt | off | bsum | bbase | enodes(u32) | P fp8 | Q fp8
    unsigned short* wp     = (unsigned short*)ws;              //    81,920 B
    int*            cnt    = (int*)(ws + 81920);               //   200,000 B
    int*            off    = (int*)(ws + 281920);              //   200,000 B
    int*            bsum   = (int*)(ws + 481920);              //     1,024 B
    int*            bbase  = (int*)(ws + 482944);              //     1,024 B
    unsigned*       enodes = (unsigned*)(ws + 483968);         // 3,200,000 B
    unsigned char*  pb     = (unsigned char*)(ws + 3683968);   // 6,400,000 B
    unsigned char*  qb     = (unsigned char*)(ws + 10083968);  // 6,400,000 B

    hipMemsetAsync(cnt, 0, 200000, stream);
    setup_kernel<<<(SETUP_TOTAL + 255) / 256, 256, 0, stream>>>(ei, W1, W2, W3, wp, cnt, out);
    pq_kernel<<<PQ_BLOCKS, 256, 0, stream>>>(x, wp, b1, pb, qb);
    scanA_kernel<<<256, 256, 0, stream>>>(cnt, off, bsum);
    scanB_kernel<<<1, 256, 0, stream>>>(bsum, bbase);
    scatter_kernel<<<(E_EDGES + 255) / 256, 256, 0, stream>>>(ei, off, bbase, enodes);
    edge_mlp_kernel<<<6250, 256, 0, stream>>>(enodes, wp, pb, qb, b2, b3, out);
    finalize_kernel<<<(int)(((long)NN * 72 + 255) / 256), 256, 0, stream>>>(x, u, batch, cnt, out);
}